// Round 3
// baseline (190.682 us; speedup 1.0000x reference)
//
#include <hip/hip_runtime.h>

typedef _Float16 half4v __attribute__((ext_vector_type(4)));
typedef _Float16 half8  __attribute__((ext_vector_type(8)));
typedef float    floatx4 __attribute__((ext_vector_type(4)));

// pooled ws layout (transposed for coalesced final): [16*11][128] fp32 = 22528 floats
__global__ __launch_bounds__(256) void knrm_zero(float* __restrict__ p) {
    p[blockIdx.x * 256 + threadIdx.x] = 0.0f;
}

__global__ __launch_bounds__(256, 4) void knrm_main(
    const int*   __restrict__ queries,    // 128 x 16
    const int*   __restrict__ documents,  // 128 x 2048
    const float* __restrict__ emb,        // 100000 x 128
    float*       __restrict__ pooled)     // [176][128] atomic accum
{
    __shared__ __align__(16) _Float16 Qs[16][136];
    __shared__ __align__(16) _Float16 Ds[4][16][136];  // wave-private tile staging
    __shared__ float qn_s[16];
    __shared__ float dn_s[4][16];
    __shared__ float pooled_s[176];

    const int tid  = threadIdx.x;
    const int b    = blockIdx.x >> 3;
    const int tok0 = (blockIdx.x & 7) * 256;

    // ---- stage Q (16 rows x 128 e): fp32 norms, fp16 into LDS ----
    {
        const int row = tid >> 4, sub = tid & 15;
        const int qi = queries[b * 16 + row];
        const float4* src = (const float4*)(emb + (size_t)qi * 128 + sub * 8);
        float4 v0 = src[0], v1 = src[1];
        half8 h;
        h[0] = (_Float16)v0.x; h[1] = (_Float16)v0.y;
        h[2] = (_Float16)v0.z; h[3] = (_Float16)v0.w;
        h[4] = (_Float16)v1.x; h[5] = (_Float16)v1.y;
        h[6] = (_Float16)v1.z; h[7] = (_Float16)v1.w;
        *(half8*)&Qs[row][sub * 8] = h;
        float ns = v0.x*v0.x + v0.y*v0.y + v0.z*v0.z + v0.w*v0.w
                 + v1.x*v1.x + v1.y*v1.y + v1.z*v1.z + v1.w*v1.w;
        ns += __shfl_xor(ns, 1); ns += __shfl_xor(ns, 2);
        ns += __shfl_xor(ns, 4); ns += __shfl_xor(ns, 8);
        if (sub == 0) qn_s[row] = sqrtf(ns);
    }
    if (tid < 176) pooled_s[tid] = 0.0f;
    __syncthreads();

    const int lane = tid & 63;
    const int wave = tid >> 6;
    const int col  = lane & 15;   // MFMA: A row m / B col n / C col
    const int quad = lane >> 4;   // MFMA: k-octet select / C row group

    // A fragments + q-norms in registers for the whole block
    half8 afrag[4];
#pragma unroll
    for (int c = 0; c < 4; ++c)
        afrag[c] = *(const half8*)&Qs[col][c * 32 + quad * 8];
    float qn[4];
#pragma unroll
    for (int r = 0; r < 4; ++r) qn[r] = qn_s[quad * 4 + r];

    float pr[4][11];
#pragma unroll
    for (int r = 0; r < 4; ++r)
#pragma unroll
        for (int k = 0; k < 11; ++k) pr[r][k] = 0.0f;

    // wave handles 64 tokens: 4 tiles x 16. Lane's token index (coalesced load):
    const int my_idx = documents[b * 2048 + tok0 + wave * 64 + lane];

    // Gather geometry: 32 consecutive lanes read one full row (coalesced).
    const int halfw = lane >> 5;   // which of the instr's 2 rows
    const int sub   = lane & 31;   // float4 chunk within the row

    for (int t = 0; t < 4; ++t) {
        // ---- coalesced gather: 8 instrs x (2 rows x 32 lanes x 16B) ----
        float4 v[8];
#pragma unroll
        for (int k = 0; k < 8; ++k) {
            const int ridx = __shfl(my_idx, t * 16 + 2 * k + halfw);
            v[k] = *(const float4*)(emb + (size_t)ridx * 128 + sub * 4);
        }
        // ---- convert fp16 -> wave-private LDS, fp32 norms ----
#pragma unroll
        for (int k = 0; k < 8; ++k) {
            const float4 a = v[k];
            half4v h;
            h[0] = (_Float16)a.x; h[1] = (_Float16)a.y;
            h[2] = (_Float16)a.z; h[3] = (_Float16)a.w;
            *(half4v*)&Ds[wave][2 * k + halfw][sub * 4] = h;
            float ns = a.x*a.x + a.y*a.y + a.z*a.z + a.w*a.w;
            ns += __shfl_xor(ns, 1);  ns += __shfl_xor(ns, 2);
            ns += __shfl_xor(ns, 4);  ns += __shfl_xor(ns, 8);
            ns += __shfl_xor(ns, 16);
            if (sub == 0) dn_s[wave][2 * k + halfw] = sqrtf(ns);
        }
        // (same-wave DS ordering: reads below are after writes above in program order)

        // ---- MFMA: 16q x 16tok ----
        floatx4 acc = {0.0f, 0.0f, 0.0f, 0.0f};
#pragma unroll
        for (int c = 0; c < 4; ++c) {
            half8 bf = *(const half8*)&Ds[wave][col][c * 32 + quad * 8];
            acc = __builtin_amdgcn_mfma_f32_16x16x32_f16(afrag[c], bf, acc, 0, 0, 0);
        }
        const float dn = dn_s[wave][col];

        // C/D layout: col = lane&15 (token), row = quad*4 + r (query)
#pragma unroll
        for (int r = 0; r < 4; ++r) {
            const float denom = qn[r] * dn + 1e-8f;
            const float sim = acc[r] * __builtin_amdgcn_rcpf(denom);
#pragma unroll
            for (int k = 0; k < 11; ++k) {
                const float tt = sim - (-1.0f + 0.2f * (float)k);
                // exp(-t^2/(2*0.1^2)) = exp2(-50*log2(e) * t^2)
                pr[r][k] += __builtin_amdgcn_exp2f(tt * tt * -72.13475204444817f);
            }
        }
    }

    // ---- block-level reduction, then 176 global atomics (transposed layout) ----
#pragma unroll
    for (int r = 0; r < 4; ++r)
#pragma unroll
        for (int k = 0; k < 11; ++k)
            atomicAdd(&pooled_s[(quad * 4 + r) * 11 + k], pr[r][k]);
    __syncthreads();
    if (tid < 176) atomicAdd(&pooled[tid * 128 + b], pooled_s[tid]);
}

__global__ __launch_bounds__(128) void knrm_final(
    const float* __restrict__ pooled,   // [176][128]
    const float* __restrict__ W,
    const float* __restrict__ bias,
    float*       __restrict__ out)
{
    const int b = threadIdx.x;   // one block of 128; loads below are lane-coalesced
    float acc = bias[0];
#pragma unroll
    for (int k = 0; k < 11; ++k) {
        float s = 0.0f;
#pragma unroll
        for (int q = 0; q < 16; ++q)
            s += __builtin_amdgcn_logf(pooled[(q * 11 + k) * 128 + b]);  // log2
        acc += s * 0.69314718055994531f * W[k];                          // * ln2
    }
    out[b] = __builtin_amdgcn_rcpf(1.0f + __builtin_amdgcn_exp2f(acc * -1.4426950408889634f));
}

extern "C" void kernel_launch(void* const* d_in, const int* in_sizes, int n_in,
                              void* d_out, int out_size, void* d_ws, size_t ws_size,
                              hipStream_t stream) {
    const int*   queries   = (const int*)d_in[0];
    const int*   documents = (const int*)d_in[1];
    const float* emb       = (const float*)d_in[2];
    const float* W         = (const float*)d_in[3];
    const float* bias      = (const float*)d_in[4];
    float* out    = (float*)d_out;
    float* pooled = (float*)d_ws;   // 22528 floats = 88 KiB

    knrm_zero<<<88, 256, 0, stream>>>(pooled);                       // 88*256 == 22528
    knrm_main<<<1024, 256, 0, stream>>>(queries, documents, emb, pooled);
    knrm_final<<<1, 128, 0, stream>>>(pooled, W, bias, out);
}

// Round 4
// 188.791 us; speedup vs baseline: 1.0100x; 1.0100x over previous
//
#include <hip/hip_runtime.h>

typedef _Float16 half4v __attribute__((ext_vector_type(4)));
typedef _Float16 half8  __attribute__((ext_vector_type(8)));
typedef float    floatx4 __attribute__((ext_vector_type(4)));

// ---------------- ws layout (fast path) ----------------
// [0, 25600000)          fp16 table: 100000 x 128 halfs
// [25600000, 26000000)   norms:      100000 floats
// [26000000, 26090112)   pooled:     [176][128] fp32 (transposed)
#define TAB_OFF    0
#define NORM_OFF   25600000
#define POOL_OFF   26000000
#define WS_NEEDED  26090112

// ---- prep: fp32 table -> fp16 table + norms (contiguous stream); zero pooled ----
__global__ __launch_bounds__(256) void knrm_prep(
    const float* __restrict__ emb,       // 100000 x 128
    _Float16*    __restrict__ tab,       // 100000 x 128
    float*       __restrict__ norms,     // 100000
    float*       __restrict__ pooled)    // 22528 floats
{
    const int tid = threadIdx.x;
    if (blockIdx.x < 88) pooled[blockIdx.x * 256 + tid] = 0.0f;

    const int lane = tid & 63;
    const int wav  = blockIdx.x * 4 + (tid >> 6);   // 8192 waves
    const int half = lane >> 5;                      // which row of the pair
    const int sub  = lane & 31;                      // float4 chunk in row

    for (int rp = wav; rp < 50000; rp += 8192) {     // 2 rows per wave-iter
        const int row = rp * 2 + half;
        const float4 v = *(const float4*)(emb + (size_t)row * 128 + sub * 4);
        half4v h;
        h[0] = (_Float16)v.x; h[1] = (_Float16)v.y;
        h[2] = (_Float16)v.z; h[3] = (_Float16)v.w;
        *(half4v*)(tab + (size_t)row * 128 + sub * 4) = h;
        float ns = v.x*v.x + v.y*v.y + v.z*v.z + v.w*v.w;
        ns += __shfl_xor(ns, 1); ns += __shfl_xor(ns, 2);
        ns += __shfl_xor(ns, 4); ns += __shfl_xor(ns, 8);
        ns += __shfl_xor(ns, 16);   // masks <32 stay within the 32-lane half
        if (sub == 0) norms[row] = sqrtf(ns);
    }
}

// ---- main (fast path): gather fp16 rows from L3-resident table ----
__global__ __launch_bounds__(256) void knrm_main(
    const int*      __restrict__ queries,    // 128 x 16
    const int*      __restrict__ documents,  // 128 x 2048
    const _Float16* __restrict__ tab,        // 100000 x 128 fp16
    const float*    __restrict__ norms,      // 100000
    float*          __restrict__ pooled)     // [176][128] atomic accum
{
    __shared__ __align__(16) _Float16 Qs[16][136];
    __shared__ __align__(16) _Float16 Ds[4][16][136];  // wave-private staging
    __shared__ float qn_s[16];
    __shared__ float pooled_s[176];

    const int tid  = threadIdx.x;
    const int b    = blockIdx.x >> 3;
    const int tok0 = (blockIdx.x & 7) * 256;

    // stage Q rows (fp16, 16 B per thread) + q-norms
    {
        const int row = tid >> 4, chunk = tid & 15;
        const int qi = queries[b * 16 + row];
        *(uint4*)&Qs[row][chunk * 8] =
            *(const uint4*)(tab + (size_t)qi * 128 + chunk * 8);
        if (tid < 16) qn_s[tid] = norms[queries[b * 16 + tid]];
    }
    if (tid < 176) pooled_s[tid] = 0.0f;
    __syncthreads();

    const int lane = tid & 63;
    const int wave = tid >> 6;
    const int col  = lane & 15;   // MFMA: A row m / B col n / C col
    const int quad = lane >> 4;   // MFMA: k-octet select / C row group

    half8 afrag[4];
#pragma unroll
    for (int c = 0; c < 4; ++c)
        afrag[c] = *(const half8*)&Qs[col][c * 32 + quad * 8];
    float qn[4];
#pragma unroll
    for (int r = 0; r < 4; ++r) qn[r] = qn_s[quad * 4 + r];

    float pr[4][11];
#pragma unroll
    for (int r = 0; r < 4; ++r)
#pragma unroll
        for (int k = 0; k < 11; ++k) pr[r][k] = 0.0f;

    // wave owns 64 tokens; norm gathered once (scattered 4B, L2-hit)
    const int   my_idx  = documents[b * 2048 + tok0 + wave * 64 + lane];
    const float my_norm = norms[my_idx];

    const int rsel  = lane >> 4;   // row-within-quad for gather (4 rows/instr)
    const int chunk = lane & 15;   // 16B chunk within row

    for (int t = 0; t < 4; ++t) {
        // gather 16 fp16 rows (256 B each): 4 instrs x 1 KB, 4 rows per instr
#pragma unroll
        for (int j = 0; j < 4; ++j) {
            const int ridx = __shfl(my_idx, t * 16 + j * 4 + rsel);
            const uint4 v = *(const uint4*)(tab + (size_t)ridx * 128 + chunk * 8);
            *(uint4*)&Ds[wave][j * 4 + rsel][chunk * 8] = v;
        }
        // same-wave DS ordering: fragment reads below follow writes in program order

        floatx4 acc = {0.0f, 0.0f, 0.0f, 0.0f};
#pragma unroll
        for (int c = 0; c < 4; ++c) {
            half8 bf = *(const half8*)&Ds[wave][col][c * 32 + quad * 8];
            acc = __builtin_amdgcn_mfma_f32_16x16x32_f16(afrag[c], bf, acc, 0, 0, 0);
        }
        const float dn = __shfl(my_norm, t * 16 + col);

        // C/D layout: col = lane&15 (token), row = quad*4 + r (query)
#pragma unroll
        for (int r = 0; r < 4; ++r) {
            const float denom = qn[r] * dn + 1e-8f;
            const float sim = acc[r] * __builtin_amdgcn_rcpf(denom);
#pragma unroll
            for (int k = 0; k < 11; ++k) {
                const float tt = sim - (-1.0f + 0.2f * (float)k);
                pr[r][k] += __builtin_amdgcn_exp2f(tt * tt * -72.13475204444817f);
            }
        }
    }

#pragma unroll
    for (int r = 0; r < 4; ++r)
#pragma unroll
        for (int k = 0; k < 11; ++k)
            atomicAdd(&pooled_s[(quad * 4 + r) * 11 + k], pr[r][k]);
    __syncthreads();
    if (tid < 176) atomicAdd(&pooled[tid * 128 + b], pooled_s[tid]);
}

// ---- fallback path (ws too small): round-3 structure, gathers fp32 directly ----
__global__ __launch_bounds__(256) void knrm_zero_fb(float* __restrict__ p) {
    p[blockIdx.x * 256 + threadIdx.x] = 0.0f;
}

__global__ __launch_bounds__(256) void knrm_main_fb(
    const int*   __restrict__ queries,
    const int*   __restrict__ documents,
    const float* __restrict__ emb,
    float*       __restrict__ pooled)    // [176][128]
{
    __shared__ __align__(16) _Float16 Qs[16][136];
    __shared__ __align__(16) _Float16 Ds[4][16][136];
    __shared__ float qn_s[16];
    __shared__ float dn_s[4][16];
    __shared__ float pooled_s[176];

    const int tid  = threadIdx.x;
    const int b    = blockIdx.x >> 3;
    const int tok0 = (blockIdx.x & 7) * 256;

    {
        const int row = tid >> 4, sub = tid & 15;
        const int qi = queries[b * 16 + row];
        const float4* src = (const float4*)(emb + (size_t)qi * 128 + sub * 8);
        float4 v0 = src[0], v1 = src[1];
        half8 h;
        h[0] = (_Float16)v0.x; h[1] = (_Float16)v0.y;
        h[2] = (_Float16)v0.z; h[3] = (_Float16)v0.w;
        h[4] = (_Float16)v1.x; h[5] = (_Float16)v1.y;
        h[6] = (_Float16)v1.z; h[7] = (_Float16)v1.w;
        *(half8*)&Qs[row][sub * 8] = h;
        float ns = v0.x*v0.x + v0.y*v0.y + v0.z*v0.z + v0.w*v0.w
                 + v1.x*v1.x + v1.y*v1.y + v1.z*v1.z + v1.w*v1.w;
        ns += __shfl_xor(ns, 1); ns += __shfl_xor(ns, 2);
        ns += __shfl_xor(ns, 4); ns += __shfl_xor(ns, 8);
        if (sub == 0) qn_s[row] = sqrtf(ns);
    }
    if (tid < 176) pooled_s[tid] = 0.0f;
    __syncthreads();

    const int lane = tid & 63;
    const int wave = tid >> 6;
    const int col  = lane & 15;
    const int quad = lane >> 4;

    half8 afrag[4];
#pragma unroll
    for (int c = 0; c < 4; ++c)
        afrag[c] = *(const half8*)&Qs[col][c * 32 + quad * 8];
    float qn[4];
#pragma unroll
    for (int r = 0; r < 4; ++r) qn[r] = qn_s[quad * 4 + r];

    float pr[4][11];
#pragma unroll
    for (int r = 0; r < 4; ++r)
#pragma unroll
        for (int k = 0; k < 11; ++k) pr[r][k] = 0.0f;

    const int my_idx = documents[b * 2048 + tok0 + wave * 64 + lane];
    const int halfw = lane >> 5;
    const int sub   = lane & 31;

    for (int t = 0; t < 4; ++t) {
        float4 v[8];
#pragma unroll
        for (int k = 0; k < 8; ++k) {
            const int ridx = __shfl(my_idx, t * 16 + 2 * k + halfw);
            v[k] = *(const float4*)(emb + (size_t)ridx * 128 + sub * 4);
        }
#pragma unroll
        for (int k = 0; k < 8; ++k) {
            const float4 a = v[k];
            half4v h;
            h[0] = (_Float16)a.x; h[1] = (_Float16)a.y;
            h[2] = (_Float16)a.z; h[3] = (_Float16)a.w;
            *(half4v*)&Ds[wave][2 * k + halfw][sub * 4] = h;
            float ns = a.x*a.x + a.y*a.y + a.z*a.z + a.w*a.w;
            ns += __shfl_xor(ns, 1);  ns += __shfl_xor(ns, 2);
            ns += __shfl_xor(ns, 4);  ns += __shfl_xor(ns, 8);
            ns += __shfl_xor(ns, 16);
            if (sub == 0) dn_s[wave][2 * k + halfw] = sqrtf(ns);
        }
        floatx4 acc = {0.0f, 0.0f, 0.0f, 0.0f};
#pragma unroll
        for (int c = 0; c < 4; ++c) {
            half8 bf = *(const half8*)&Ds[wave][col][c * 32 + quad * 8];
            acc = __builtin_amdgcn_mfma_f32_16x16x32_f16(afrag[c], bf, acc, 0, 0, 0);
        }
        const float dn = dn_s[wave][col];
#pragma unroll
        for (int r = 0; r < 4; ++r) {
            const float denom = qn[r] * dn + 1e-8f;
            const float sim = acc[r] * __builtin_amdgcn_rcpf(denom);
#pragma unroll
            for (int k = 0; k < 11; ++k) {
                const float tt = sim - (-1.0f + 0.2f * (float)k);
                pr[r][k] += __builtin_amdgcn_exp2f(tt * tt * -72.13475204444817f);
            }
        }
    }
#pragma unroll
    for (int r = 0; r < 4; ++r)
#pragma unroll
        for (int k = 0; k < 11; ++k)
            atomicAdd(&pooled_s[(quad * 4 + r) * 11 + k], pr[r][k]);
    __syncthreads();
    if (tid < 176) atomicAdd(&pooled[tid * 128 + b], pooled_s[tid]);
}

// ---- final: 176 log-sums per batch, coalesced over [feature][batch] ----
__global__ __launch_bounds__(128) void knrm_final(
    const float* __restrict__ pooled,   // [176][128]
    const float* __restrict__ W,
    const float* __restrict__ bias,
    float*       __restrict__ out)
{
    const int b = threadIdx.x;
    float acc = bias[0];
#pragma unroll
    for (int k = 0; k < 11; ++k) {
        float s = 0.0f;
#pragma unroll
        for (int q = 0; q < 16; ++q)
            s += __builtin_amdgcn_logf(pooled[(q * 11 + k) * 128 + b]);  // log2
        acc += s * 0.69314718055994531f * W[k];                          // * ln2
    }
    out[b] = __builtin_amdgcn_rcpf(1.0f + __builtin_amdgcn_exp2f(acc * -1.4426950408889634f));
}

extern "C" void kernel_launch(void* const* d_in, const int* in_sizes, int n_in,
                              void* d_out, int out_size, void* d_ws, size_t ws_size,
                              hipStream_t stream) {
    const int*   queries   = (const int*)d_in[0];
    const int*   documents = (const int*)d_in[1];
    const float* emb       = (const float*)d_in[2];
    const float* W         = (const float*)d_in[3];
    const float* bias      = (const float*)d_in[4];
    float* out = (float*)d_out;
    char*  ws  = (char*)d_ws;

    if (ws_size >= (size_t)WS_NEEDED) {
        _Float16* tab    = (_Float16*)(ws + TAB_OFF);
        float*    norms  = (float*)(ws + NORM_OFF);
        float*    pooled = (float*)(ws + POOL_OFF);
        knrm_prep<<<2048, 256, 0, stream>>>(emb, tab, norms, pooled);
        knrm_main<<<1024, 256, 0, stream>>>(queries, documents, tab, norms, pooled);
        knrm_final<<<1, 128, 0, stream>>>(pooled, W, bias, out);
    } else {
        float* pooled = (float*)ws;   // 88 KiB
        knrm_zero_fb<<<88, 256, 0, stream>>>(pooled);
        knrm_main_fb<<<1024, 256, 0, stream>>>(queries, documents, emb, pooled);
        knrm_final<<<1, 128, 0, stream>>>(pooled, W, bias, out);
    }
}

// Round 5
// 186.239 us; speedup vs baseline: 1.0239x; 1.0137x over previous
//
#include <hip/hip_runtime.h>

typedef _Float16 half4v __attribute__((ext_vector_type(4)));
typedef _Float16 half8  __attribute__((ext_vector_type(8)));
typedef float    floatx4 __attribute__((ext_vector_type(4)));

// ---------------- ws layout (fast path) ----------------
// [0, 25600000)           normalized fp16 table: 100000 x 128 halfs
// [25600000, 25690112)    pooled: [176][128] fp32 (transposed)
#define TAB_OFF    0
#define POOL_OFF   25600000
#define WS_NEEDED  25690112

// ---- prep: stream emb, write NORMALIZED fp16 table (zero rows -> zeros); zero pooled ----
__global__ __launch_bounds__(256) void knrm_prep(
    const float* __restrict__ emb,       // 100000 x 128
    _Float16*    __restrict__ tab,       // 100000 x 128 (normalized)
    float*       __restrict__ pooled)    // 22528 floats
{
    const int tid = threadIdx.x;
    if (blockIdx.x < 88) pooled[blockIdx.x * 256 + tid] = 0.0f;

    const int lane = tid & 63;
    const int wav  = blockIdx.x * 4 + (tid >> 6);    // 8192 waves
    const int half = lane >> 5;                      // which row of the pair
    const int sub  = lane & 31;                      // float4 chunk in row

    for (int rp = wav; rp < 50000; rp += 8192) {     // 2 rows per wave-iter
        const int row = rp * 2 + half;
        const float4 v = *(const float4*)(emb + (size_t)row * 128 + sub * 4);
        float ns = v.x*v.x + v.y*v.y + v.z*v.z + v.w*v.w;
        ns += __shfl_xor(ns, 1); ns += __shfl_xor(ns, 2);
        ns += __shfl_xor(ns, 4); ns += __shfl_xor(ns, 8);
        ns += __shfl_xor(ns, 16);   // masks <32 stay within the 32-lane half
        const float sc = (ns > 0.0f) ? __frsqrt_rn(ns) : 0.0f;
        half4v h;
        h[0] = (_Float16)(v.x * sc); h[1] = (_Float16)(v.y * sc);
        h[2] = (_Float16)(v.z * sc); h[3] = (_Float16)(v.w * sc);
        *(half4v*)(tab + (size_t)row * 128 + sub * 4) = h;
    }
}

// ---- main: gather normalized fp16 rows; sim comes straight from MFMA ----
__global__ __launch_bounds__(256) void knrm_main(
    const int*      __restrict__ queries,    // 128 x 16
    const int*      __restrict__ documents,  // 128 x 2048
    const _Float16* __restrict__ tab,        // 100000 x 128 normalized fp16
    float*          __restrict__ pooled)     // [176][128] atomic accum
{
    __shared__ __align__(16) _Float16 Qs[16][136];
    __shared__ __align__(16) _Float16 Ds[4][16][136];  // wave-private staging
    __shared__ float pooled_s[176];

    const int tid  = threadIdx.x;
    const int b    = blockIdx.x >> 3;
    const int tok0 = (blockIdx.x & 7) * 256;

    // stage normalized Q rows (16 x 256 B, coalesced)
    {
        const int row = tid >> 4, chunk = tid & 15;
        const int qi = queries[b * 16 + row];
        *(uint4*)&Qs[row][chunk * 8] =
            *(const uint4*)(tab + (size_t)qi * 128 + chunk * 8);
    }
    if (tid < 176) pooled_s[tid] = 0.0f;
    __syncthreads();

    const int lane = tid & 63;
    const int wave = tid >> 6;
    const int col  = lane & 15;   // MFMA: A row m / B col n / C col
    const int quad = lane >> 4;   // MFMA: k-octet select / C row group

    half8 afrag[4];
#pragma unroll
    for (int c = 0; c < 4; ++c)
        afrag[c] = *(const half8*)&Qs[col][c * 32 + quad * 8];

    float pr[4][11];
#pragma unroll
    for (int r = 0; r < 4; ++r)
#pragma unroll
        for (int k = 0; k < 11; ++k) pr[r][k] = 0.0f;

    // wave owns 64 tokens
    const int my_idx = documents[b * 2048 + tok0 + wave * 64 + lane];

    const int rsel  = lane >> 4;   // row-within-instr (4 rows/instr)
    const int chunk = lane & 15;   // 16B chunk within row

    // ---- hoist ALL 16 row-gathers (independent; maximal MLP) ----
    uint4 sreg[16];
#pragma unroll
    for (int i = 0; i < 16; ++i) {
        const int ridx = __shfl(my_idx, i * 4 + rsel);
        sreg[i] = *(const uint4*)(tab + (size_t)ridx * 128 + chunk * 8);
    }

    for (int t = 0; t < 4; ++t) {
        // stage 16 rows into wave-private LDS (from already-fetched regs)
#pragma unroll
        for (int j = 0; j < 4; ++j)
            *(uint4*)&Ds[wave][j * 4 + rsel][chunk * 8] = sreg[t * 4 + j];
        // same-wave DS ordering: fragment reads below follow writes in program order

        floatx4 acc = {0.0f, 0.0f, 0.0f, 0.0f};
#pragma unroll
        for (int c = 0; c < 4; ++c) {
            half8 bf = *(const half8*)&Ds[wave][col][c * 32 + quad * 8];
            acc = __builtin_amdgcn_mfma_f32_16x16x32_f16(afrag[c], bf, acc, 0, 0, 0);
        }

        // C/D layout: col = lane&15 (token), row = quad*4 + r (query); sim = acc directly
#pragma unroll
        for (int r = 0; r < 4; ++r) {
            const float sim = acc[r];
#pragma unroll
            for (int k = 0; k < 11; ++k) {
                const float tt = sim - (-1.0f + 0.2f * (float)k);
                pr[r][k] += __builtin_amdgcn_exp2f(tt * tt * -72.13475204444817f);
            }
        }
    }

#pragma unroll
    for (int r = 0; r < 4; ++r)
#pragma unroll
        for (int k = 0; k < 11; ++k)
            atomicAdd(&pooled_s[(quad * 4 + r) * 11 + k], pr[r][k]);
    __syncthreads();
    if (tid < 176) atomicAdd(&pooled[tid * 128 + b], pooled_s[tid]);
}

// ---- fallback path (ws too small): fp32 direct gather with inline norms ----
__global__ __launch_bounds__(256) void knrm_zero_fb(float* __restrict__ p) {
    p[blockIdx.x * 256 + threadIdx.x] = 0.0f;
}

__global__ __launch_bounds__(256) void knrm_main_fb(
    const int*   __restrict__ queries,
    const int*   __restrict__ documents,
    const float* __restrict__ emb,
    float*       __restrict__ pooled)    // [176][128]
{
    __shared__ __align__(16) _Float16 Qs[16][136];
    __shared__ __align__(16) _Float16 Ds[4][16][136];
    __shared__ float qn_s[16];
    __shared__ float dn_s[4][16];
    __shared__ float pooled_s[176];

    const int tid  = threadIdx.x;
    const int b    = blockIdx.x >> 3;
    const int tok0 = (blockIdx.x & 7) * 256;

    {
        const int row = tid >> 4, sub = tid & 15;
        const int qi = queries[b * 16 + row];
        const float4* src = (const float4*)(emb + (size_t)qi * 128 + sub * 8);
        float4 v0 = src[0], v1 = src[1];
        half8 h;
        h[0] = (_Float16)v0.x; h[1] = (_Float16)v0.y;
        h[2] = (_Float16)v0.z; h[3] = (_Float16)v0.w;
        h[4] = (_Float16)v1.x; h[5] = (_Float16)v1.y;
        h[6] = (_Float16)v1.z; h[7] = (_Float16)v1.w;
        *(half8*)&Qs[row][sub * 8] = h;
        float ns = v0.x*v0.x + v0.y*v0.y + v0.z*v0.z + v0.w*v0.w
                 + v1.x*v1.x + v1.y*v1.y + v1.z*v1.z + v1.w*v1.w;
        ns += __shfl_xor(ns, 1); ns += __shfl_xor(ns, 2);
        ns += __shfl_xor(ns, 4); ns += __shfl_xor(ns, 8);
        if (sub == 0) qn_s[row] = sqrtf(ns);
    }
    if (tid < 176) pooled_s[tid] = 0.0f;
    __syncthreads();

    const int lane = tid & 63;
    const int wave = tid >> 6;
    const int col  = lane & 15;
    const int quad = lane >> 4;

    half8 afrag[4];
#pragma unroll
    for (int c = 0; c < 4; ++c)
        afrag[c] = *(const half8*)&Qs[col][c * 32 + quad * 8];
    float qn[4];
#pragma unroll
    for (int r = 0; r < 4; ++r) qn[r] = qn_s[quad * 4 + r];

    float pr[4][11];
#pragma unroll
    for (int r = 0; r < 4; ++r)
#pragma unroll
        for (int k = 0; k < 11; ++k) pr[r][k] = 0.0f;

    const int my_idx = documents[b * 2048 + tok0 + wave * 64 + lane];
    const int halfw = lane >> 5;
    const int sub   = lane & 31;

    for (int t = 0; t < 4; ++t) {
        float4 v[8];
#pragma unroll
        for (int k = 0; k < 8; ++k) {
            const int ridx = __shfl(my_idx, t * 16 + 2 * k + halfw);
            v[k] = *(const float4*)(emb + (size_t)ridx * 128 + sub * 4);
        }
#pragma unroll
        for (int k = 0; k < 8; ++k) {
            const float4 a = v[k];
            half4v h;
            h[0] = (_Float16)a.x; h[1] = (_Float16)a.y;
            h[2] = (_Float16)a.z; h[3] = (_Float16)a.w;
            *(half4v*)&Ds[wave][2 * k + halfw][sub * 4] = h;
            float ns = a.x*a.x + a.y*a.y + a.z*a.z + a.w*a.w;
            ns += __shfl_xor(ns, 1);  ns += __shfl_xor(ns, 2);
            ns += __shfl_xor(ns, 4);  ns += __shfl_xor(ns, 8);
            ns += __shfl_xor(ns, 16);
            if (sub == 0) dn_s[wave][2 * k + halfw] = sqrtf(ns);
        }
        floatx4 acc = {0.0f, 0.0f, 0.0f, 0.0f};
#pragma unroll
        for (int c = 0; c < 4; ++c) {
            half8 bf = *(const half8*)&Ds[wave][col][c * 32 + quad * 8];
            acc = __builtin_amdgcn_mfma_f32_16x16x32_f16(afrag[c], bf, acc, 0, 0, 0);
        }
        const float dn = dn_s[wave][col];
#pragma unroll
        for (int r = 0; r < 4; ++r) {
            const float denom = qn[r] * dn + 1e-8f;
            const float sim = acc[r] * __builtin_amdgcn_rcpf(denom);
#pragma unroll
            for (int k = 0; k < 11; ++k) {
                const float tt = sim - (-1.0f + 0.2f * (float)k);
                pr[r][k] += __builtin_amdgcn_exp2f(tt * tt * -72.13475204444817f);
            }
        }
    }
#pragma unroll
    for (int r = 0; r < 4; ++r)
#pragma unroll
        for (int k = 0; k < 11; ++k)
            atomicAdd(&pooled_s[(quad * 4 + r) * 11 + k], pr[r][k]);
    __syncthreads();
    if (tid < 176) atomicAdd(&pooled[tid * 128 + b], pooled_s[tid]);
}

// ---- final: 176 log-sums per batch, coalesced over [feature][batch] ----
__global__ __launch_bounds__(128) void knrm_final(
    const float* __restrict__ pooled,   // [176][128]
    const float* __restrict__ W,
    const float* __restrict__ bias,
    float*       __restrict__ out)
{
    const int b = threadIdx.x;
    float acc = bias[0];
#pragma unroll
    for (int k = 0; k < 11; ++k) {
        float s = 0.0f;
#pragma unroll
        for (int q = 0; q < 16; ++q)
            s += __builtin_amdgcn_logf(pooled[(q * 11 + k) * 128 + b]);  // log2
        acc += s * 0.69314718055994531f * W[k];                          // * ln2
    }
    out[b] = __builtin_amdgcn_rcpf(1.0f + __builtin_amdgcn_exp2f(acc * -1.4426950408889634f));
}

extern "C" void kernel_launch(void* const* d_in, const int* in_sizes, int n_in,
                              void* d_out, int out_size, void* d_ws, size_t ws_size,
                              hipStream_t stream) {
    const int*   queries   = (const int*)d_in[0];
    const int*   documents = (const int*)d_in[1];
    const float* emb       = (const float*)d_in[2];
    const float* W         = (const float*)d_in[3];
    const float* bias      = (const float*)d_in[4];
    float* out = (float*)d_out;
    char*  ws  = (char*)d_ws;

    if (ws_size >= (size_t)WS_NEEDED) {
        _Float16* tab    = (_Float16*)(ws + TAB_OFF);
        float*    pooled = (float*)(ws + POOL_OFF);
        knrm_prep<<<2048, 256, 0, stream>>>(emb, tab, pooled);
        knrm_main<<<1024, 256, 0, stream>>>(queries, documents, tab, pooled);
        knrm_final<<<1, 128, 0, stream>>>(pooled, W, bias, out);
    } else {
        float* pooled = (float*)ws;   // 88 KiB
        knrm_zero_fb<<<88, 256, 0, stream>>>(pooled);
        knrm_main_fb<<<1024, 256, 0, stream>>>(queries, documents, emb, pooled);
        knrm_final<<<1, 128, 0, stream>>>(pooled, W, bias, out);
    }
}